// Round 5
// baseline (261.817 us; speedup 1.0000x reference)
//
#include <hip/hip_runtime.h>
#include <math.h>

// Blinn-Phong shading, N=4194304 elements of (light,normal,view) 3-vectors.
// Memory-bound streaming: 36 B in + 12 B out per element -> 201 MB, ~30 us floor.
// R2: exact-traffic LDS staging (FETCH=1.0x input). R4: HW transcendentals
// (v_log/v_exp via __builtin_amdgcn_{logf,exp2f}; exact at nh=0) + v_rsq.
// R5: deep load pipeline - 4 elem/thread, 9 global_load_dwordx4 issued
// back-to-back per thread (R1's issue structure sustained ~6 TB/s; R2's
// 2.25 loads/thread only ~3.1 TB/s). LDS buffer reused for output staging.

#define BLOCK 256
#define EPT 4
#define TILE (BLOCK * EPT)   // 1024 elements per block

__global__ __launch_bounds__(BLOCK) void blinn_phong_kernel(
    const float* __restrict__ in,   // (n, 3, 3)
    const float* __restrict__ kd,   // (3,)
    const float* __restrict__ ks,   // (3,)
    const float* __restrict__ pp,   // (1,)
    float* __restrict__ out,        // (n, 3)
    int n)
{
    __shared__ float s_mem[TILE * 9];   // 36 KB; reused for 12 KB out staging

    const int tid = threadIdx.x;
    const long long blk0 = (long long)blockIdx.x * TILE;

    // ---- stage: 2304 float4 per block, 9 per thread, all in flight at once ----
    const float4* gin = (const float4*)(in + blk0 * 9);
    float4* s4 = (float4*)s_mem;
    const long long total4 = ((long long)n * 9) >> 2;   // n*9 divisible by 4
    const long long base4 = blk0 * 9 / 4;               // 2304 * bid
    float4 r[9];
#pragma unroll
    for (int i = 0; i < 9; ++i) {
        if (base4 + tid + i * BLOCK < total4) r[i] = gin[tid + i * BLOCK];
    }
#pragma unroll
    for (int i = 0; i < 9; ++i) s4[tid + i * BLOCK] = r[i];
    __syncthreads();

    // ---- compute: thread t handles elements t, t+256, t+512, t+768 ----
    // (stride-9 float LDS reads at lane-stride 9: odd stride -> conflict-free)
    const float kd0 = kd[0], kd1 = kd[1], kd2 = kd[2];
    const float ks0 = ks[0], ks1 = ks[1], ks2 = ks[2];
    const float p = pp[0];

    float o[EPT][3];
#pragma unroll
    for (int m = 0; m < EPT; ++m) {
        const int j = tid + m * BLOCK;
        const float* e = s_mem + j * 9;
        float Lx = e[0], Ly = e[1], Lz = e[2];
        float Nx = e[3], Ny = e[4], Nz = e[5];
        float Vx = e[6], Vy = e[7], Vz = e[8];

        float ln = fmaxf(0.0f, Lx * Nx + Ly * Ny + Lz * Nz);

        float hx = Lx + Vx, hy = Ly + Vy, hz = Lz + Vz;
        float hh = hx * hx + hy * hy + hz * hz;
        // max(sqrt(hh), 1e-12) == sqrt(max(hh, 1e-24)) -> single v_rsq_f32
        float inv = rsqrtf(fmaxf(hh, 1e-24f));

        float nh = fmaxf(0.0f, (Nx * hx + Ny * hy + Nz * hz) * inv);
        // nh >= 0; v_log_f32(0)=-inf -> v_exp_f32(-inf)=0 == 0^p
        float spec = __builtin_amdgcn_exp2f(p * __builtin_amdgcn_logf(nh));

        o[m][0] = ks0 * spec + kd0 * ln;
        o[m][1] = ks1 * spec + kd1 * ln;
        o[m][2] = ks2 * spec + kd2 * ln;
    }
    __syncthreads();   // all s_in reads complete before reuse as out staging

    // ---- out staging into reused LDS (lane-stride 3: odd -> conflict-free) ----
#pragma unroll
    for (int m = 0; m < EPT; ++m) {
        const int j = tid + m * BLOCK;
        s_mem[3 * j + 0] = o[m][0];
        s_mem[3 * j + 1] = o[m][1];
        s_mem[3 * j + 2] = o[m][2];
    }
    __syncthreads();

    // ---- store: 768 coalesced float4 per block ----
    float4* gout = (float4*)(out + blk0 * 3);
    const long long out_total4 = ((long long)n * 3) >> 2;
    const long long out_base4 = blk0 * 3 / 4;           // 768 * bid
#pragma unroll
    for (int m = 0; m < 3; ++m) {
        if (out_base4 + tid + m * BLOCK < out_total4)
            gout[tid + m * BLOCK] = s4[tid + m * BLOCK];
    }
}

extern "C" void kernel_launch(void* const* d_in, const int* in_sizes, int n_in,
                              void* d_out, int out_size, void* d_ws, size_t ws_size,
                              hipStream_t stream) {
    const float* in = (const float*)d_in[0];
    const float* kd = (const float*)d_in[1];
    const float* ks = (const float*)d_in[2];
    const float* pp = (const float*)d_in[3];
    float* out = (float*)d_out;

    int n = in_sizes[0] / 9;
    int grid = (n + TILE - 1) / TILE;
    blinn_phong_kernel<<<grid, BLOCK, 0, stream>>>(in, kd, ks, pp, out, n);
}

// Round 6
// 229.658 us; speedup vs baseline: 1.1400x; 1.1400x over previous
//
#include <hip/hip_runtime.h>
#include <math.h>

// Blinn-Phong shading, N=4194304 elements of (light,normal,view) 3-vectors.
// Memory-bound streaming: 36 B in + 12 B out per element -> 201 MB, ~30 us floor.
// R6: no-LDS, no-barrier structure modeled on the 6.3 TB/s float4-copy ubench.
//   4 elements = 9 float4 in, 3 float4 out per thread, all contiguous per lane.
//   Per-wave the 9 loads cover one contiguous 9216 B span -> FETCH stays 1.0x
//   (L1 merges the stride-144B lane pattern; each 64B line fetched once).
//   R5 lesson: MLP was never the limit (R2 had 18 MB in flight vs 2.6 MB
//   BW-latency product); the LDS phase barriers were. Remove them entirely.
// Math: v_rsq via max(sqrt(hh),EPS)==sqrt(max(hh,EPS^2));
//   powf -> v_log_f32/v_exp_f32 (__builtin_amdgcn_{logf,exp2f}; exact at nh=0).

#define BLOCK 256
#define EPT 4   // elements per thread; 4*9 floats = 9 float4, 4*3 = 3 float4

__global__ __launch_bounds__(BLOCK) void blinn_phong_kernel(
    const float* __restrict__ in,   // (n, 3, 3)
    const float* __restrict__ kd,   // (3,)
    const float* __restrict__ ks,   // (3,)
    const float* __restrict__ pp,   // (1,)
    float* __restrict__ out,        // (n, 3)
    int n)
{
    const long long g = (long long)blockIdx.x * BLOCK + threadIdx.x;
    const long long e0 = g * EPT;
    if (e0 >= n) return;            // n % 4 == 0 -> whole thread in/out of bounds

    const float4* __restrict__ gin4 = (const float4*)in;
    float4* __restrict__ gout4 = (float4*)out;

    // ---- 9 contiguous float4 loads (144 B per lane), all independent ----
    float4 r[9];
    const long long ib = g * 9;
#pragma unroll
    for (int i = 0; i < 9; ++i) r[i] = gin4[ib + i];
    const float* f = (const float*)r;   // f[9m + k]: element m, component k

    const float kd0 = kd[0], kd1 = kd[1], kd2 = kd[2];
    const float ks0 = ks[0], ks1 = ks[1], ks2 = ks[2];
    const float p = pp[0];

    float4 o[3];
    float* ov = (float*)o;              // 12 output floats

#pragma unroll
    for (int m = 0; m < EPT; ++m) {
        const float Lx = f[9*m+0], Ly = f[9*m+1], Lz = f[9*m+2];
        const float Nx = f[9*m+3], Ny = f[9*m+4], Nz = f[9*m+5];
        const float Vx = f[9*m+6], Vy = f[9*m+7], Vz = f[9*m+8];

        const float ln = fmaxf(0.0f, Lx * Nx + Ly * Ny + Lz * Nz);

        const float hx = Lx + Vx, hy = Ly + Vy, hz = Lz + Vz;
        const float hh = hx * hx + hy * hy + hz * hz;
        const float inv = rsqrtf(fmaxf(hh, 1e-24f));   // single v_rsq_f32

        const float nh = fmaxf(0.0f, (Nx * hx + Ny * hy + Nz * hz) * inv);
        // nh >= 0; v_log_f32(0) = -inf -> v_exp_f32(-inf) = 0 == 0^p
        const float spec = __builtin_amdgcn_exp2f(p * __builtin_amdgcn_logf(nh));

        ov[3*m + 0] = ks0 * spec + kd0 * ln;
        ov[3*m + 1] = ks1 * spec + kd1 * ln;
        ov[3*m + 2] = ks2 * spec + kd2 * ln;
    }

    // ---- 3 contiguous float4 stores (48 B per lane) ----
    const long long ob = g * 3;
#pragma unroll
    for (int m = 0; m < 3; ++m) gout4[ob + m] = o[m];
}

extern "C" void kernel_launch(void* const* d_in, const int* in_sizes, int n_in,
                              void* d_out, int out_size, void* d_ws, size_t ws_size,
                              hipStream_t stream) {
    const float* in = (const float*)d_in[0];
    const float* kd = (const float*)d_in[1];
    const float* ks = (const float*)d_in[2];
    const float* pp = (const float*)d_in[3];
    float* out = (float*)d_out;

    int n = in_sizes[0] / 9;
    int threads_needed = (n + EPT - 1) / EPT;
    int grid = (threads_needed + BLOCK - 1) / BLOCK;
    blinn_phong_kernel<<<grid, BLOCK, 0, stream>>>(in, kd, ks, pp, out, n);
}